// Round 11
// baseline (1080.102 us; speedup 1.0000x reference)
//
#include <hip/hip_runtime.h>
#include <hip/hip_bf16.h>

#define N_TAG 128
#define T_LEN 512
#define START_TAG 126
#define STOP_TAG 127

typedef __attribute__((ext_vector_type(8))) __bf16 bf16x8;
typedef __attribute__((ext_vector_type(4))) float f32x4;

// Split-direction exp-space CRF DP, zero-communication MFMA steps.
// Round 11: 4 batches/block -> 8 DP waves + 1 gold wave (576 thr), grid 128.
// 2 DP waves per SIMD: independent chains fill each other's latency stalls
// (round 10 was 1 wave/SIMD: ~1000cy/step of exposed chain latency).
// Also: acc zero-init removed (kk=0 MFMA uses persistent zero C-quad).
__global__ __launch_bounds__(576, 1)
void crf_split_kernel(const float* __restrict__ feats,
                      const float* __restrict__ trans,
                      const int* __restrict__ tags,
                      float* __restrict__ out) {
  const int tid = threadIdx.x;
  const int wid = tid >> 6;
  const int lane = tid & 63;
  const int bbase = blockIdx.x * 4;

  __shared__ float Uf[4][N_TAG];
  __shared__ float Wb[4][N_TAG];
  __shared__ float LZ[8];
  __shared__ float GOLD[4];

  if (wid == 8) {
    // ---- gold wave: 16 lanes per batch ----
    const int grp = lane >> 4, tl = lane & 15;
    const int b = bbase + grp;
    const int* tg = tags + (size_t)b * T_LEN;
    const float* fg = feats + (size_t)b * T_LEN * N_TAG;
    float gsum = 0.f;
    for (int t = tl; t < T_LEN; t += 16) {
      int tag = tg[t];
      int prev = (t == 0) ? START_TAG : tg[t - 1];
      gsum += trans[(size_t)tag * N_TAG + prev] + fg[(size_t)t * N_TAG + tag];
      if (t == T_LEN - 1) gsum += trans[STOP_TAG * N_TAG + tag];
    }
#pragma unroll
    for (int s = 8; s; s >>= 1) gsum += __shfl_xor(gsum, s);
    if (tl == 0) GOLD[grp] = gsum;
    __syncthreads();
    // ---- combine ----
#pragma unroll
    for (int bL = 0; bL < 4; ++bL) {
      float sd = Uf[bL][lane] * Wb[bL][lane] +
                 Uf[bL][lane + 64] * Wb[bL][lane + 64];
#pragma unroll
      for (int s = 32; s; s >>= 1) sd += __shfl_xor(sd, s);
      if (lane == 0)
        out[bbase + bL] = __logf(sd) + LZ[2 * bL] + LZ[2 * bL + 1] - GOLD[bL];
    }
    return;
  }

  // ---- main DP waves: wid = 2*bL + dir (dir 0 fwd, 1 bwd) ----
  const int bL = wid >> 1, dir = wid & 1;
  const int batch = bbase + bL;
  const int n = lane & 15, g = lane >> 4;
  const float* fbase = feats + (size_t)batch * T_LEN * N_TAG;
  const int T0 = dir ? 510 : 0;
  const int TS = dir ? -1 : 1;
  const int ib = 32 * g;  // bpermute base byte address

  // ---- A fragments: tile mt holds E rows tau(mt, ridx); lane supplies
  //      row ridx=n, elements k = 32kk+8g+j. fwd: E[tau][k]; bwd: E[k][tau].
  bf16x8 A[8][4];
#pragma unroll
  for (int mt = 0; mt < 8; ++mt) {
    const int tau = 32 * (mt >> 1) + 8 * (n >> 2) + 4 * (mt & 1) + (n & 3);
#pragma unroll
    for (int kk = 0; kk < 4; ++kk) {
      bf16x8 v;
      if (dir == 0) {
        const float* p = trans + (size_t)tau * N_TAG + 32 * kk + 8 * g;
        f32x4 x = *(const f32x4*)p;
        f32x4 y = *(const f32x4*)(p + 4);
        v[0] = (__bf16)__expf(x[0]); v[1] = (__bf16)__expf(x[1]);
        v[2] = (__bf16)__expf(x[2]); v[3] = (__bf16)__expf(x[3]);
        v[4] = (__bf16)__expf(y[0]); v[5] = (__bf16)__expf(y[1]);
        v[6] = (__bf16)__expf(y[2]); v[7] = (__bf16)__expf(y[3]);
      } else {
#pragma unroll
        for (int j = 0; j < 8; ++j)
          v[j] = (__bf16)__expf(trans[(size_t)(32 * kk + 8 * g + j) * N_TAG + tau]);
      }
      A[mt][kk] = v;
    }
  }

  // ---- B init ----
  bf16x8 Bv[4];
#pragma unroll
  for (int kk = 0; kk < 4; ++kk) {
    bf16x8 z;
#pragma unroll
    for (int j = 0; j < 8; ++j) z[j] = (__bf16)0.0f;
    Bv[kk] = z;
  }
  if (dir == 0) {
    // u_{-1} = one-hot(START=126): tag 126 -> kk=3, g=3, j=6
    if (g == 3) Bv[3][6] = (__bf16)1.0f;
  } else {
    // b0 = ef_511 ⊙ s, s_j = exp(trans[STOP][j]); tag = 32kk+8g+j
    const float* s127 = trans + (size_t)STOP_TAG * N_TAG;
    const float* f511 = fbase + (size_t)(T_LEN - 1) * N_TAG;
#pragma unroll
    for (int kk = 0; kk < 4; ++kk) {
      const int off = 32 * kk + 8 * g;
      f32x4 s0 = *(const f32x4*)(s127 + off);
      f32x4 s1 = *(const f32x4*)(s127 + off + 4);
      f32x4 e0 = *(const f32x4*)(f511 + off);
      f32x4 e1 = *(const f32x4*)(f511 + off + 4);
      bf16x8 v;
      v[0] = (__bf16)__expf(s0[0] + e0[0]); v[1] = (__bf16)__expf(s0[1] + e0[1]);
      v[2] = (__bf16)__expf(s0[2] + e0[2]); v[3] = (__bf16)__expf(s0[3] + e0[3]);
      v[4] = (__bf16)__expf(s1[0] + e1[0]); v[5] = (__bf16)__expf(s1[1] + e1[1]);
      v[6] = (__bf16)__expf(s1[2] + e1[2]); v[7] = (__bf16)__expf(s1[3] + e1[3]);
      Bv[kk] = v;
    }
  }

  const f32x4 FZ = {0.f, 0.f, 0.f, 0.f};

  // ---- feat ring: slot s holds row t_cur (t==s mod 4); 2 dwords/lane ----
  float Lr[4][2];
#pragma unroll
  for (int s = 0; s < 4; ++s) {
    const float* rp = fbase + (size_t)(T0 + TS * s) * N_TAG;
    Lr[s][0] = rp[lane];
    Lr[s][1] = rp[lane + 64];
  }
  Lr[0][0] = __expf(Lr[0][0]);
  Lr[0][1] = __expf(Lr[0][1]);
  float logZ = 0.0f;

  // EF[mt][r] = ef[tau(mt,4g+r)]; tau = 32a+8g+4bb+r (a=mt>>1, bb=mt&1):
  // a<2 -> reg0 lane tau; a>=2 -> reg1 lane tau-64. Imm-offset bpermutes.
#define BPERM(DST, SLOT)                                                     \
  {                                                                          \
    _Pragma("unroll") for (int a = 0; a < 4; ++a) {                          \
      int sv_ = __float_as_int((a < 2) ? Lr[SLOT][0] : Lr[SLOT][1]);         \
      _Pragma("unroll") for (int bb = 0; bb < 2; ++bb) {                     \
        _Pragma("unroll") for (int r = 0; r < 4; ++r) {                      \
          int w_ = __builtin_amdgcn_ds_bpermute(                             \
              ib + 128 * (a & 1) + 16 * bb + 4 * r, sv_);                    \
          DST[2 * a + bb][r] = __int_as_float(w_);                           \
        }                                                                    \
      }                                                                      \
    }                                                                        \
  }

#define RENORM(ACC)                                                          \
  {                                                                          \
    float mx_ = ACC[0][0];                                                   \
    _Pragma("unroll") for (int mt = 0; mt < 8; ++mt)                         \
        mx_ = fmaxf(mx_, fmaxf(fmaxf(ACC[mt][0], ACC[mt][1]),                \
                               fmaxf(ACC[mt][2], ACC[mt][3])));              \
    mx_ = fmaxf(mx_, __shfl_xor(mx_, 16));                                   \
    mx_ = fmaxf(mx_, __shfl_xor(mx_, 32));                                   \
    int eb_ = __float_as_int(mx_) & 0x7f800000;                              \
    float inv_ = __int_as_float(0x7f000000 - eb_); /* exact 2^-a */          \
    logZ += (float)((eb_ >> 23) - 127) * 0.69314718056f;                     \
    _Pragma("unroll") for (int mt = 0; mt < 8; ++mt) {                       \
      ACC[mt][0] *= inv_; ACC[mt][1] *= inv_;                                \
      ACC[mt][2] *= inv_; ACC[mt][3] *= inv_;                                \
    }                                                                        \
  }

#define ITER(S, SX, KP4, DOREN)                                              \
  {                                                                          \
    f32x4 EF[8];                                                             \
    BPERM(EF, S);                                                            \
    f32x4 acc[8];                                                            \
    _Pragma("unroll") for (int mt = 0; mt < 8; ++mt)                         \
        acc[mt] = __builtin_amdgcn_mfma_f32_16x16x32_bf16(                   \
            A[mt][0], Bv[0], FZ, 0, 0, 0);                                   \
    _Pragma("unroll") for (int kk = 1; kk < 4; ++kk) {                       \
      _Pragma("unroll") for (int mt = 0; mt < 8; ++mt)                       \
          acc[mt] = __builtin_amdgcn_mfma_f32_16x16x32_bf16(                 \
              A[mt][kk], Bv[kk], acc[mt], 0, 0, 0);                          \
    }                                                                        \
    _Pragma("unroll") for (int mt = 0; mt < 8; ++mt) {                       \
      acc[mt][0] *= EF[mt][0]; acc[mt][1] *= EF[mt][1];                      \
      acc[mt][2] *= EF[mt][2]; acc[mt][3] *= EF[mt][3];                      \
    }                                                                        \
    if (DOREN) RENORM(acc);                                                  \
    _Pragma("unroll") for (int kk = 0; kk < 4; ++kk) {                       \
      bf16x8 nb;                                                             \
      nb[0] = (__bf16)acc[2 * kk][0];     nb[1] = (__bf16)acc[2 * kk][1];    \
      nb[2] = (__bf16)acc[2 * kk][2];     nb[3] = (__bf16)acc[2 * kk][3];    \
      nb[4] = (__bf16)acc[2 * kk + 1][0]; nb[5] = (__bf16)acc[2 * kk + 1][1];\
      nb[6] = (__bf16)acc[2 * kk + 1][2]; nb[7] = (__bf16)acc[2 * kk + 1][3];\
      Bv[kk] = nb;                                                           \
    }                                                                        \
    Lr[SX][0] = __expf(Lr[SX][0]); /* next step's ef (landed 3 iters ago) */ \
    Lr[SX][1] = __expf(Lr[SX][1]);                                           \
    {                                                                        \
      const float* rp_ = fbase + (size_t)(T0 + TS * (KP4)) * N_TAG;          \
      Lr[S][0] = rp_[lane]; /* refill slot: 4-iter lookahead */              \
      Lr[S][1] = rp_[lane + 64];                                             \
    }                                                                        \
  }

  // ---- 255 full steps + tail: 256 MFMA steps total ----
  for (int kb = 0; kb < 63; ++kb) {
    const int k0 = kb * 4;
    ITER(0, 1, k0 + 4, false);
    ITER(1, 2, k0 + 5, false);
    ITER(2, 3, k0 + 6, false);
    ITER(3, 0, k0 + 7, true);
  }
  ITER(0, 1, 256, false);  // k=252
  ITER(1, 2, 257, false);  // k=253
  ITER(2, 3, 258, false);  // k=254

  // ---- tail (k=255): fwd multiplies ef_255; bwd keeps raw E^T·b ----
  f32x4 upF[8];
  {
    f32x4 EF[8];
    BPERM(EF, 3);
    f32x4 acc[8];
#pragma unroll
    for (int mt = 0; mt < 8; ++mt)
      acc[mt] = __builtin_amdgcn_mfma_f32_16x16x32_bf16(A[mt][0], Bv[0], FZ,
                                                        0, 0, 0);
#pragma unroll
    for (int kk = 1; kk < 4; ++kk) {
#pragma unroll
      for (int mt = 0; mt < 8; ++mt)
        acc[mt] = __builtin_amdgcn_mfma_f32_16x16x32_bf16(A[mt][kk], Bv[kk],
                                                          acc[mt], 0, 0, 0);
    }
    if (dir == 0) {
#pragma unroll
      for (int mt = 0; mt < 8; ++mt) {
        acc[mt][0] *= EF[mt][0]; acc[mt][1] *= EF[mt][1];
        acc[mt][2] *= EF[mt][2]; acc[mt][3] *= EF[mt][3];
      }
    }
    RENORM(acc);  // final normalization so the dot can't overflow f32
#pragma unroll
    for (int mt = 0; mt < 8; ++mt) upF[mt] = acc[mt];
  }

  // ---- publish final vectors (plain tag order) ----
  float* dst = (dir == 0) ? Uf[bL] : Wb[bL];
  if (n == 0) {
#pragma unroll
    for (int mt = 0; mt < 8; ++mt) {
      const int base = 32 * (mt >> 1) + 8 * g + 4 * (mt & 1);
#pragma unroll
      for (int r = 0; r < 4; ++r) dst[base + r] = upF[mt][r];
    }
  }
  if (lane == 0) LZ[wid] = logZ;
  __syncthreads();
#undef ITER
#undef RENORM
#undef BPERM
}

extern "C" void kernel_launch(void* const* d_in, const int* in_sizes, int n_in,
                              void* d_out, int out_size, void* d_ws, size_t ws_size,
                              hipStream_t stream) {
  const float* feats = (const float*)d_in[0];
  const float* trans = (const float*)d_in[1];
  const int* tags = (const int*)d_in[2];
  float* out = (float*)d_out;
  int B = in_sizes[0] / (T_LEN * N_TAG);  // 512
  crf_split_kernel<<<B / 4, 576, 0, stream>>>(feats, trans, tags, out);
}

// Round 14
// 280.379 us; speedup vs baseline: 3.8523x; 3.8523x over previous
//
#include <hip/hip_runtime.h>
#include <hip/hip_bf16.h>

#define N_TAG 128
#define T_LEN 512
#define START_TAG 126
#define STOP_TAG 127

typedef __attribute__((ext_vector_type(8))) __bf16 bf16x8;
typedef __attribute__((ext_vector_type(4))) float f32x4;

// Split-direction exp-space CRF DP, zero-communication MFMA steps (r10 math,
// verified absmax 0). Round 12 changes ONLY the feat path:
//  - feats staged to LDS via async global_load_lds (16-step double buffer per
//    DP wave, counted vmcnt(8): waits target loads issued 16 steps earlier)
//  - EF gather via 8x broadcast ds_read_b128 using tau(mt,4g+r)=32a+8g+4bb+r
//    (contiguous r-quads) -> replaces 32 ds_bpermute + register ring
//  - exp applied in-lane after the LDS read (off the MFMA dependency chain)
// Block: 320 thr = 4 DP waves (2 batches x fwd/bwd) + 1 gold wave. Grid 256.
__global__ __launch_bounds__(320, 1)
void crf_split_kernel(const float* __restrict__ feats,
                      const float* __restrict__ trans,
                      const int* __restrict__ tags,
                      float* __restrict__ out) {
  const int tid = threadIdx.x;
  const int wid = tid >> 6;
  const int lane = tid & 63;
  const int bbase = blockIdx.x * 2;

  __shared__ __align__(16) float stage_lds[4][2][2048];  // [DPwave][buf][16 rows x 128]
  __shared__ float Uf[2][N_TAG];
  __shared__ float Wb[2][N_TAG];
  __shared__ float LZ[4];
  __shared__ float GOLD[2];

  if (wid == 4) {
    // ---- gold wave: lanes 0-31 batch 0, lanes 32-63 batch 1 ----
    const int half = lane >> 5, tl = lane & 31;
    const int b = bbase + half;
    const int* tg = tags + (size_t)b * T_LEN;
    const float* fg = feats + (size_t)b * T_LEN * N_TAG;
    float gsum = 0.f;
    for (int t = tl; t < T_LEN; t += 32) {
      int tag = tg[t];
      int prev = (t == 0) ? START_TAG : tg[t - 1];
      gsum += trans[(size_t)tag * N_TAG + prev] + fg[(size_t)t * N_TAG + tag];
      if (t == T_LEN - 1) gsum += trans[STOP_TAG * N_TAG + tag];
    }
#pragma unroll
    for (int s = 16; s; s >>= 1) gsum += __shfl_xor(gsum, s);
    if (tl == 0) GOLD[half] = gsum;
    __syncthreads();
#pragma unroll
    for (int bL = 0; bL < 2; ++bL) {
      float sd = Uf[bL][lane] * Wb[bL][lane] +
                 Uf[bL][lane + 64] * Wb[bL][lane + 64];
#pragma unroll
      for (int s = 32; s; s >>= 1) sd += __shfl_xor(sd, s);
      if (lane == 0)
        out[bbase + bL] = __logf(sd) + LZ[2 * bL] + LZ[2 * bL + 1] - GOLD[bL];
    }
    return;
  }

  // ---- main DP waves: wid = 2*bL + dir (dir 0 fwd, 1 bwd) ----
  const int bL = wid >> 1, dir = wid & 1;
  const int batch = bbase + bL;
  const int n = lane & 15, g = lane >> 4;
  const float* fbase = feats + (size_t)batch * T_LEN * N_TAG;

  // ---- A fragments: tile mt holds E rows tau(mt, ridx); lane supplies
  //      row ridx=n, elements k = 32kk+8g+j. fwd: E[tau][k]; bwd: E[k][tau].
  bf16x8 A[8][4];
#pragma unroll
  for (int mt = 0; mt < 8; ++mt) {
    const int tau = 32 * (mt >> 1) + 8 * (n >> 2) + 4 * (mt & 1) + (n & 3);
#pragma unroll
    for (int kk = 0; kk < 4; ++kk) {
      bf16x8 v;
      if (dir == 0) {
        const float* p = trans + (size_t)tau * N_TAG + 32 * kk + 8 * g;
        f32x4 x = *(const f32x4*)p;
        f32x4 y = *(const f32x4*)(p + 4);
        v[0] = (__bf16)__expf(x[0]); v[1] = (__bf16)__expf(x[1]);
        v[2] = (__bf16)__expf(x[2]); v[3] = (__bf16)__expf(x[3]);
        v[4] = (__bf16)__expf(y[0]); v[5] = (__bf16)__expf(y[1]);
        v[6] = (__bf16)__expf(y[2]); v[7] = (__bf16)__expf(y[3]);
      } else {
#pragma unroll
        for (int j = 0; j < 8; ++j)
          v[j] = (__bf16)__expf(trans[(size_t)(32 * kk + 8 * g + j) * N_TAG + tau]);
      }
      A[mt][kk] = v;
    }
  }

  // ---- B init ----
  bf16x8 Bv[4];
#pragma unroll
  for (int kk = 0; kk < 4; ++kk) {
    bf16x8 z;
#pragma unroll
    for (int j = 0; j < 8; ++j) z[j] = (__bf16)0.0f;
    Bv[kk] = z;
  }
  if (dir == 0) {
    if (g == 3) Bv[3][6] = (__bf16)1.0f;  // one-hot START=126: kk=3,g=3,j=6
  } else {
    const float* s127 = trans + (size_t)STOP_TAG * N_TAG;
    const float* f511 = fbase + (size_t)(T_LEN - 1) * N_TAG;
#pragma unroll
    for (int kk = 0; kk < 4; ++kk) {
      const int off = 32 * kk + 8 * g;
      f32x4 s0 = *(const f32x4*)(s127 + off);
      f32x4 s1 = *(const f32x4*)(s127 + off + 4);
      f32x4 e0 = *(const f32x4*)(f511 + off);
      f32x4 e1 = *(const f32x4*)(f511 + off + 4);
      bf16x8 v;
      v[0] = (__bf16)__expf(s0[0] + e0[0]); v[1] = (__bf16)__expf(s0[1] + e0[1]);
      v[2] = (__bf16)__expf(s0[2] + e0[2]); v[3] = (__bf16)__expf(s0[3] + e0[3]);
      v[4] = (__bf16)__expf(s1[0] + e1[0]); v[5] = (__bf16)__expf(s1[1] + e1[1]);
      v[6] = (__bf16)__expf(s1[2] + e1[2]); v[7] = (__bf16)__expf(s1[3] + e1[3]);
      Bv[kk] = v;
    }
  }

  const f32x4 FZ = {0.f, 0.f, 0.f, 0.f};
  float logZ = 0.0f;
  f32x4 upF[8];

  // ---- async staging: block M = 16 feat rows (8KB) via 8 global_load_lds ----
#define STAGE(M_)                                                             \
  {                                                                           \
    const int br_ = dir ? (495 - 16 * (M_)) : (16 * (M_));                    \
    const float* gs_ = fbase + (size_t)br_ * N_TAG + lane * 4;                \
    float* lb_ = &stage_lds[wid][(M_) & 1][0];                                \
    _Pragma("unroll") for (int i_ = 0; i_ < 8; ++i_)                          \
        __builtin_amdgcn_global_load_lds(                                     \
            (const __attribute__((address_space(1))) unsigned int*)(gs_ +     \
                                                                    i_ * 256),\
            (__attribute__((address_space(3))) unsigned int*)(lb_ + i_ * 256),\
            16, 0, 0);                                                        \
  }

#define RENORM(ACC)                                                          \
  {                                                                          \
    float mx_ = ACC[0][0];                                                   \
    _Pragma("unroll") for (int mt_ = 0; mt_ < 8; ++mt_)                      \
        mx_ = fmaxf(mx_, fmaxf(fmaxf(ACC[mt_][0], ACC[mt_][1]),              \
                               fmaxf(ACC[mt_][2], ACC[mt_][3])));            \
    mx_ = fmaxf(mx_, __shfl_xor(mx_, 16));                                   \
    mx_ = fmaxf(mx_, __shfl_xor(mx_, 32));                                   \
    int eb_ = __float_as_int(mx_) & 0x7f800000;                              \
    float inv_ = __int_as_float(0x7f000000 - eb_); /* exact 2^-a */          \
    logZ += (float)((eb_ >> 23) - 127) * 0.69314718056f;                     \
    _Pragma("unroll") for (int mt_ = 0; mt_ < 8; ++mt_) {                    \
      ACC[mt_][0] *= inv_; ACC[mt_][1] *= inv_;                              \
      ACC[mt_][2] *= inv_; ACC[mt_][3] *= inv_;                              \
    }                                                                        \
  }

#define PACKB(ACC)                                                           \
  {                                                                          \
    _Pragma("unroll") for (int kk_ = 0; kk_ < 4; ++kk_) {                    \
      bf16x8 nb_;                                                            \
      nb_[0] = (__bf16)ACC[2 * kk_][0];     nb_[1] = (__bf16)ACC[2 * kk_][1];\
      nb_[2] = (__bf16)ACC[2 * kk_][2];     nb_[3] = (__bf16)ACC[2 * kk_][3];\
      nb_[4] = (__bf16)ACC[2 * kk_ + 1][0]; nb_[5] = (__bf16)ACC[2 * kk_ + 1][1];\
      nb_[6] = (__bf16)ACC[2 * kk_ + 1][2]; nb_[7] = (__bf16)ACC[2 * kk_ + 1][3];\
      Bv[kk_] = nb_;                                                         \
    }                                                                        \
  }

  // One DP step consuming staged row at slot SOFF of buffer BUF.
  // EF[mt][r] = exp(row[32*(mt>>1) + 8g + 4*(mt&1) + r]) -> f32x4 idx 8a+2g+bb.
#define STEP(BUF, SOFF, DOREN)                                               \
  {                                                                          \
    const f32x4* row_ = (const f32x4*)&stage_lds[wid][BUF][(SOFF) * 128];    \
    f32x4 Qv_[8];                                                            \
    _Pragma("unroll") for (int a_ = 0; a_ < 4; ++a_)                         \
        _Pragma("unroll") for (int bb_ = 0; bb_ < 2; ++bb_)                  \
            Qv_[2 * a_ + bb_] = row_[8 * a_ + 2 * g + bb_];                  \
    f32x4 acc_[8];                                                           \
    _Pragma("unroll") for (int mt_ = 0; mt_ < 8; ++mt_)                      \
        acc_[mt_] = __builtin_amdgcn_mfma_f32_16x16x32_bf16(A[mt_][0], Bv[0],\
                                                            FZ, 0, 0, 0);    \
    _Pragma("unroll") for (int kk_ = 1; kk_ < 4; ++kk_)                      \
        _Pragma("unroll") for (int mt_ = 0; mt_ < 8; ++mt_)                  \
            acc_[mt_] = __builtin_amdgcn_mfma_f32_16x16x32_bf16(             \
                A[mt_][kk_], Bv[kk_], acc_[mt_], 0, 0, 0);                   \
    _Pragma("unroll") for (int mt_ = 0; mt_ < 8; ++mt_) {                    \
      acc_[mt_][0] *= __expf(Qv_[mt_][0]);                                   \
      acc_[mt_][1] *= __expf(Qv_[mt_][1]);                                   \
      acc_[mt_][2] *= __expf(Qv_[mt_][2]);                                   \
      acc_[mt_][3] *= __expf(Qv_[mt_][3]);                                   \
    }                                                                        \
    if (DOREN) RENORM(acc_);                                                 \
    PACKB(acc_);                                                             \
  }

  // prologue: stage blocks 0,1
  STAGE(0);
  STAGE(1);

  for (int m = 0; m < 15; ++m) {
    asm volatile("s_waitcnt vmcnt(8)" ::: "memory");  // block m landed
    const int bufc = m & 1;
#pragma unroll
    for (int q = 0; q < 4; ++q) {
      {
        const int o0 = 4 * q + 0, s0 = dir ? 15 - o0 : o0;
        STEP(bufc, s0, false);
      }
      {
        const int o1 = 4 * q + 1, s1 = dir ? 15 - o1 : o1;
        STEP(bufc, s1, false);
      }
      {
        const int o2 = 4 * q + 2, s2 = dir ? 15 - o2 : o2;
        STEP(bufc, s2, false);
      }
      {
        const int o3 = 4 * q + 3, s3 = dir ? 15 - o3 : o3;
        STEP(bufc, s3, true);
      }
    }
    asm volatile("s_waitcnt lgkmcnt(0)" ::: "memory");  // reads retired before
    if (m + 2 <= 15) STAGE(m + 2);                      // overwriting this buf
  }

  // ---- block 15: 15 steps + tail ----
  asm volatile("s_waitcnt vmcnt(0)" ::: "memory");
#pragma unroll
  for (int o = 0; o < 15; ++o) {
    const int s = dir ? 15 - o : o;
    STEP(1, s, (o & 3) == 3);
  }
  {
    // tail (k=255): fwd multiplies ef_255 (slot 15); bwd keeps raw E^T b
    f32x4 acc[8];
#pragma unroll
    for (int mt = 0; mt < 8; ++mt)
      acc[mt] = __builtin_amdgcn_mfma_f32_16x16x32_bf16(A[mt][0], Bv[0], FZ,
                                                        0, 0, 0);
#pragma unroll
    for (int kk = 1; kk < 4; ++kk)
#pragma unroll
      for (int mt = 0; mt < 8; ++mt)
        acc[mt] = __builtin_amdgcn_mfma_f32_16x16x32_bf16(A[mt][kk], Bv[kk],
                                                          acc[mt], 0, 0, 0);
    if (dir == 0) {
      const f32x4* row = (const f32x4*)&stage_lds[wid][1][15 * 128];
#pragma unroll
      for (int a = 0; a < 4; ++a)
#pragma unroll
        for (int bb = 0; bb < 2; ++bb) {
          f32x4 q = row[8 * a + 2 * g + bb];
          acc[2 * a + bb][0] *= __expf(q[0]);
          acc[2 * a + bb][1] *= __expf(q[1]);
          acc[2 * a + bb][2] *= __expf(q[2]);
          acc[2 * a + bb][3] *= __expf(q[3]);
        }
    }
    RENORM(acc);
#pragma unroll
    for (int mt = 0; mt < 8; ++mt) upF[mt] = acc[mt];
  }

  // ---- publish final vectors (plain tag order) ----
  float* dst = (dir == 0) ? Uf[bL] : Wb[bL];
  if (n == 0) {
#pragma unroll
    for (int mt = 0; mt < 8; ++mt) {
      const int base = 32 * (mt >> 1) + 8 * g + 4 * (mt & 1);
#pragma unroll
      for (int r = 0; r < 4; ++r) dst[base + r] = upF[mt][r];
    }
  }
  if (lane == 0) LZ[wid] = logZ;
  __syncthreads();
#undef STEP
#undef PACKB
#undef RENORM
#undef STAGE
}

extern "C" void kernel_launch(void* const* d_in, const int* in_sizes, int n_in,
                              void* d_out, int out_size, void* d_ws, size_t ws_size,
                              hipStream_t stream) {
  const float* feats = (const float*)d_in[0];
  const float* trans = (const float*)d_in[1];
  const int* tags = (const int*)d_in[2];
  float* out = (float*)d_out;
  int B = in_sizes[0] / (T_LEN * N_TAG);  // 512
  crf_split_kernel<<<B / 2, 320, 0, stream>>>(feats, trans, tags, out);
}

// Round 17
// 234.347 us; speedup vs baseline: 4.6090x; 1.1964x over previous
//
#include <hip/hip_runtime.h>
#include <hip/hip_bf16.h>

#define N_TAG 128
#define T_LEN 512
#define START_TAG 126
#define STOP_TAG 127

typedef __attribute__((ext_vector_type(8))) __bf16 bf16x8;
typedef __attribute__((ext_vector_type(4))) float f32x4;

// Split-direction exp-space CRF DP, zero-communication MFMA steps (r10 math,
// verified absmax 0, 149us). Round 15: pack 2 DP chains per SIMD.
// Block = 512 thr = 8 DP waves (4 batches x fwd/bwd), grid 128.
// waves_per_eu(2,2): r10 wave uses ~252 regs (124 VGPR + 128 AGPR A-frags);
// 2x252 = 504 <= 512-reg SIMD pool -> 2 waves/SIMD co-resident, each chain's
// ~800cy/step dependency stall filled by the other chain's issue.
// Gold wave removed: fwd wave sums gold over t in [0,256), bwd over [256,512).
__global__ __attribute__((amdgpu_flat_work_group_size(512, 512),
                          amdgpu_waves_per_eu(2, 2)))
void crf_split_kernel(const float* __restrict__ feats,
                      const float* __restrict__ trans,
                      const int* __restrict__ tags,
                      float* __restrict__ out) {
  const int tid = threadIdx.x;
  const int wid = tid >> 6;
  const int lane = tid & 63;
  const int bbase = blockIdx.x * 4;

  __shared__ float Uf[4][N_TAG];
  __shared__ float Wb[4][N_TAG];
  __shared__ float LZ[8];
  __shared__ float GOLDF[4], GOLDB[4];

  // ---- DP waves: wid = 2*bL + dir (dir 0 fwd, 1 bwd) ----
  const int bL = wid >> 1, dir = wid & 1;
  const int batch = bbase + bL;
  const int n = lane & 15, g = lane >> 4;
  const float* fbase = feats + (size_t)batch * T_LEN * N_TAG;
  const int* tg = tags + (size_t)batch * T_LEN;
  const int T0 = dir ? 510 : 0;
  const int TS = dir ? -1 : 1;
  const int ib = 32 * g;  // bpermute base byte address

  // ---- A fragments: tile mt holds E rows tau(mt, ridx); lane supplies
  //      row ridx=n, elements k = 32kk+8g+j. fwd: E[tau][k]; bwd: E[k][tau].
  bf16x8 A[8][4];
#pragma unroll
  for (int mt = 0; mt < 8; ++mt) {
    const int tau = 32 * (mt >> 1) + 8 * (n >> 2) + 4 * (mt & 1) + (n & 3);
#pragma unroll
    for (int kk = 0; kk < 4; ++kk) {
      bf16x8 v;
      if (dir == 0) {
        const float* p = trans + (size_t)tau * N_TAG + 32 * kk + 8 * g;
        f32x4 x = *(const f32x4*)p;
        f32x4 y = *(const f32x4*)(p + 4);
        v[0] = (__bf16)__expf(x[0]); v[1] = (__bf16)__expf(x[1]);
        v[2] = (__bf16)__expf(x[2]); v[3] = (__bf16)__expf(x[3]);
        v[4] = (__bf16)__expf(y[0]); v[5] = (__bf16)__expf(y[1]);
        v[6] = (__bf16)__expf(y[2]); v[7] = (__bf16)__expf(y[3]);
      } else {
#pragma unroll
        for (int j = 0; j < 8; ++j)
          v[j] = (__bf16)__expf(trans[(size_t)(32 * kk + 8 * g + j) * N_TAG + tau]);
      }
      A[mt][kk] = v;
    }
  }

  // ---- B init ----
  bf16x8 Bv[4];
#pragma unroll
  for (int kk = 0; kk < 4; ++kk) {
    bf16x8 z;
#pragma unroll
    for (int j = 0; j < 8; ++j) z[j] = (__bf16)0.0f;
    Bv[kk] = z;
  }
  if (dir == 0) {
    if (g == 3) Bv[3][6] = (__bf16)1.0f;  // one-hot START=126: kk=3,g=3,j=6
  } else {
    const float* s127 = trans + (size_t)STOP_TAG * N_TAG;
    const float* f511 = fbase + (size_t)(T_LEN - 1) * N_TAG;
#pragma unroll
    for (int kk = 0; kk < 4; ++kk) {
      const int off = 32 * kk + 8 * g;
      f32x4 s0 = *(const f32x4*)(s127 + off);
      f32x4 s1 = *(const f32x4*)(s127 + off + 4);
      f32x4 e0 = *(const f32x4*)(f511 + off);
      f32x4 e1 = *(const f32x4*)(f511 + off + 4);
      bf16x8 v;
      v[0] = (__bf16)__expf(s0[0] + e0[0]); v[1] = (__bf16)__expf(s0[1] + e0[1]);
      v[2] = (__bf16)__expf(s0[2] + e0[2]); v[3] = (__bf16)__expf(s0[3] + e0[3]);
      v[4] = (__bf16)__expf(s1[0] + e1[0]); v[5] = (__bf16)__expf(s1[1] + e1[1]);
      v[6] = (__bf16)__expf(s1[2] + e1[2]); v[7] = (__bf16)__expf(s1[3] + e1[3]);
      Bv[kk] = v;
    }
  }

  const f32x4 FZ = {0.f, 0.f, 0.f, 0.f};

  // ---- feat ring: slot s holds row t_cur (t==s mod 4); 2 dwords/lane ----
  float Lr[4][2];
#pragma unroll
  for (int s = 0; s < 4; ++s) {
    const float* rp = fbase + (size_t)(T0 + TS * s) * N_TAG;
    Lr[s][0] = rp[lane];
    Lr[s][1] = rp[lane + 64];
  }
  Lr[0][0] = __expf(Lr[0][0]);
  Lr[0][1] = __expf(Lr[0][1]);
  float logZ = 0.0f;

  // EF[mt][r] = ef[tau(mt,4g+r)]; tau = 32a+8g+4bb+r (a=mt>>1, bb=mt&1):
  // a<2 -> reg0 lane tau; a>=2 -> reg1 lane tau-64. Imm-offset bpermutes.
#define BPERM(DST, SLOT)                                                     \
  {                                                                          \
    _Pragma("unroll") for (int a = 0; a < 4; ++a) {                          \
      int sv_ = __float_as_int((a < 2) ? Lr[SLOT][0] : Lr[SLOT][1]);         \
      _Pragma("unroll") for (int bb = 0; bb < 2; ++bb) {                     \
        _Pragma("unroll") for (int r = 0; r < 4; ++r) {                      \
          int w_ = __builtin_amdgcn_ds_bpermute(                             \
              ib + 128 * (a & 1) + 16 * bb + 4 * r, sv_);                    \
          DST[2 * a + bb][r] = __int_as_float(w_);                           \
        }                                                                    \
      }                                                                      \
    }                                                                        \
  }

#define RENORM(ACC)                                                          \
  {                                                                          \
    float mx_ = ACC[0][0];                                                   \
    _Pragma("unroll") for (int mt = 0; mt < 8; ++mt)                         \
        mx_ = fmaxf(mx_, fmaxf(fmaxf(ACC[mt][0], ACC[mt][1]),                \
                               fmaxf(ACC[mt][2], ACC[mt][3])));              \
    mx_ = fmaxf(mx_, __shfl_xor(mx_, 16));                                   \
    mx_ = fmaxf(mx_, __shfl_xor(mx_, 32));                                   \
    int eb_ = __float_as_int(mx_) & 0x7f800000;                              \
    float inv_ = __int_as_float(0x7f000000 - eb_); /* exact 2^-a */          \
    logZ += (float)((eb_ >> 23) - 127) * 0.69314718056f;                     \
    _Pragma("unroll") for (int mt = 0; mt < 8; ++mt) {                       \
      ACC[mt][0] *= inv_; ACC[mt][1] *= inv_;                                \
      ACC[mt][2] *= inv_; ACC[mt][3] *= inv_;                                \
    }                                                                        \
  }

#define ITER(S, SX, KP4, DOREN)                                              \
  {                                                                          \
    f32x4 EF[8];                                                             \
    BPERM(EF, S);                                                            \
    f32x4 acc[8];                                                            \
    _Pragma("unroll") for (int mt = 0; mt < 8; ++mt)                         \
        acc[mt] = __builtin_amdgcn_mfma_f32_16x16x32_bf16(                   \
            A[mt][0], Bv[0], FZ, 0, 0, 0);                                   \
    _Pragma("unroll") for (int kk = 1; kk < 4; ++kk) {                       \
      _Pragma("unroll") for (int mt = 0; mt < 8; ++mt)                       \
          acc[mt] = __builtin_amdgcn_mfma_f32_16x16x32_bf16(                 \
              A[mt][kk], Bv[kk], acc[mt], 0, 0, 0);                          \
    }                                                                        \
    _Pragma("unroll") for (int mt = 0; mt < 8; ++mt) {                       \
      acc[mt][0] *= EF[mt][0]; acc[mt][1] *= EF[mt][1];                      \
      acc[mt][2] *= EF[mt][2]; acc[mt][3] *= EF[mt][3];                      \
    }                                                                        \
    if (DOREN) RENORM(acc);                                                  \
    _Pragma("unroll") for (int kk = 0; kk < 4; ++kk) {                       \
      bf16x8 nb;                                                             \
      nb[0] = (__bf16)acc[2 * kk][0];     nb[1] = (__bf16)acc[2 * kk][1];    \
      nb[2] = (__bf16)acc[2 * kk][2];     nb[3] = (__bf16)acc[2 * kk][3];    \
      nb[4] = (__bf16)acc[2 * kk + 1][0]; nb[5] = (__bf16)acc[2 * kk + 1][1];\
      nb[6] = (__bf16)acc[2 * kk + 1][2]; nb[7] = (__bf16)acc[2 * kk + 1][3];\
      Bv[kk] = nb;                                                           \
    }                                                                        \
    Lr[SX][0] = __expf(Lr[SX][0]); /* next step's ef (landed 3 iters ago) */ \
    Lr[SX][1] = __expf(Lr[SX][1]);                                           \
    {                                                                        \
      const float* rp_ = fbase + (size_t)(T0 + TS * (KP4)) * N_TAG;          \
      Lr[S][0] = rp_[lane]; /* refill slot: 4-iter lookahead */              \
      Lr[S][1] = rp_[lane + 64];                                             \
    }                                                                        \
  }

  // ---- 255 full steps + tail: 256 MFMA steps total ----
  for (int kb = 0; kb < 63; ++kb) {
    const int k0 = kb * 4;
    ITER(0, 1, k0 + 4, false);
    ITER(1, 2, k0 + 5, false);
    ITER(2, 3, k0 + 6, false);
    ITER(3, 0, k0 + 7, true);
  }
  ITER(0, 1, 256, false);  // k=252
  ITER(1, 2, 257, false);  // k=253
  ITER(2, 3, 258, false);  // k=254

  // ---- tail (k=255): fwd multiplies ef_255; bwd keeps raw E^T·b ----
  f32x4 upF[8];
  {
    f32x4 EF[8];
    BPERM(EF, 3);
    f32x4 acc[8];
#pragma unroll
    for (int mt = 0; mt < 8; ++mt)
      acc[mt] = __builtin_amdgcn_mfma_f32_16x16x32_bf16(A[mt][0], Bv[0], FZ,
                                                        0, 0, 0);
#pragma unroll
    for (int kk = 1; kk < 4; ++kk) {
#pragma unroll
      for (int mt = 0; mt < 8; ++mt)
        acc[mt] = __builtin_amdgcn_mfma_f32_16x16x32_bf16(A[mt][kk], Bv[kk],
                                                          acc[mt], 0, 0, 0);
    }
    if (dir == 0) {
#pragma unroll
      for (int mt = 0; mt < 8; ++mt) {
        acc[mt][0] *= EF[mt][0]; acc[mt][1] *= EF[mt][1];
        acc[mt][2] *= EF[mt][2]; acc[mt][3] *= EF[mt][3];
      }
    }
    RENORM(acc);  // final normalization so the dot can't overflow f32
#pragma unroll
    for (int mt = 0; mt < 8; ++mt) upF[mt] = acc[mt];
  }

  // ---- publish final vectors (plain tag order) ----
  float* dst = (dir == 0) ? Uf[bL] : Wb[bL];
  if (n == 0) {
#pragma unroll
    for (int mt = 0; mt < 8; ++mt) {
      const int base = 32 * (mt >> 1) + 8 * g + 4 * (mt & 1);
#pragma unroll
      for (int r = 0; r < 4; ++r) dst[base + r] = upF[mt][r];
    }
  }
  if (lane == 0) LZ[wid] = logZ;

  // ---- gold partial: fwd wave t in [0,256), bwd wave t in [256,512) ----
  {
    float gsum = 0.f;
    const int tstart = dir ? 256 : 0;
#pragma unroll
    for (int q = 0; q < 4; ++q) {
      const int t = tstart + 64 * q + lane;
      int tag = tg[t];
      int prev = (t == 0) ? START_TAG : tg[t - 1];
      gsum += trans[(size_t)tag * N_TAG + prev] + fbase[(size_t)t * N_TAG + tag];
      if (t == T_LEN - 1) gsum += trans[STOP_TAG * N_TAG + tag];
    }
#pragma unroll
    for (int s = 32; s; s >>= 1) gsum += __shfl_xor(gsum, s);
    if (lane == 0) {
      if (dir == 0) GOLDF[bL] = gsum; else GOLDB[bL] = gsum;
    }
  }
  __syncthreads();

  // ---- combine (fwd waves only): out[b] = log(Uf·Wb) + logZf + logZb - gold
  if (dir == 0) {
    float sd = Uf[bL][lane] * Wb[bL][lane] +
               Uf[bL][lane + 64] * Wb[bL][lane + 64];
#pragma unroll
    for (int s = 32; s; s >>= 1) sd += __shfl_xor(sd, s);
    if (lane == 0)
      out[batch] = __logf(sd) + LZ[2 * bL] + LZ[2 * bL + 1] -
                   (GOLDF[bL] + GOLDB[bL]);
  }
#undef ITER
#undef RENORM
#undef BPERM
}

extern "C" void kernel_launch(void* const* d_in, const int* in_sizes, int n_in,
                              void* d_out, int out_size, void* d_ws, size_t ws_size,
                              hipStream_t stream) {
  const float* feats = (const float*)d_in[0];
  const float* trans = (const float*)d_in[1];
  const int* tags = (const int*)d_in[2];
  float* out = (float*)d_out;
  int B = in_sizes[0] / (T_LEN * N_TAG);  // 512
  crf_split_kernel<<<B / 4, 512, 0, stream>>>(feats, trans, tags, out);
}

// Round 18
// 181.823 us; speedup vs baseline: 5.9404x; 1.2889x over previous
//
#include <hip/hip_runtime.h>
#include <hip/hip_bf16.h>

#define N_TAG 128
#define T_LEN 512
#define START_TAG 126
#define STOP_TAG 127
#define PADC 136  // bf16 elems per u-column (272B stride): kills 16-way bank conflict

typedef __attribute__((ext_vector_type(8))) __bf16 bf16x8;
typedef __attribute__((ext_vector_type(4))) float f32x4;

// LDS-only barrier: global (ring-refill) loads stay in flight across it.
#define BAR() asm volatile("s_waitcnt lgkmcnt(0)\n\ts_barrier" ::: "memory")

// Round 18: 2-wave M-split chains. Block = 1 batch x 1 dir, 128 thr (2 waves),
// grid 1024 -> 2048 DP waves = 2/SIMD on ALL 256 CUs (r17 showed co-residency
// gains 1.32x but 8-wave blocks waste half the chip; only 1024 chains exist,
// so widen each chain to 2 waves instead). Wave h owns output rows [64h,64h+64):
// 16 MFMA/step, A-frags 64 VGPR. Halves exchange 64x16 bf16 u-slices through a
// double-buffered LDS buffer, 1 barrier/step. Renorm: cross-wave max via LDS
// (extra barrier every 4th step), same scalar as r10 -> identical numerics.
// fwd/bwd chains meet in ws; combine kernel does log(u.w)+LZ-gold.
__global__ __launch_bounds__(128, 2)
void crf_dp_kernel(const float* __restrict__ feats,
                   const float* __restrict__ trans,
                   const int* __restrict__ tags,
                   float* __restrict__ ws) {
  const int tid = threadIdx.x;
  const int h = tid >> 6;  // M-split half
  const int lane = tid & 63;
  const int n = lane & 15, g = lane >> 4;
  const int b = blockIdx.x >> 1;
  const int dir = blockIdx.x & 1;
  const float* fbase = feats + (size_t)b * T_LEN * N_TAG;
  const int* tg = tags + (size_t)b * T_LEN;
  const int T0 = dir ? 510 : 0;
  const int TS = dir ? -1 : 1;

  __shared__ __bf16 u_lds[2][16 * PADC];
  __shared__ float MX[2][16];
  __shared__ float GLD[2];

  // ---- A-frags: tile mt covers rows 64h+16mt+[0,16); lane (n,g) holds
  //      A[64h+16mt+n][32kk+8g+j], j=0..7. fwd A=exp(trans); bwd A=exp(trans)^T.
  bf16x8 A[4][4];
#pragma unroll
  for (int mt = 0; mt < 4; ++mt) {
    const int row = 64 * h + 16 * mt + n;
#pragma unroll
    for (int kk = 0; kk < 4; ++kk) {
      bf16x8 v;
      if (dir == 0) {
        const float* p = trans + (size_t)row * N_TAG + 32 * kk + 8 * g;
        f32x4 x = *(const f32x4*)p;
        f32x4 y = *(const f32x4*)(p + 4);
        v[0] = (__bf16)__expf(x[0]); v[1] = (__bf16)__expf(x[1]);
        v[2] = (__bf16)__expf(x[2]); v[3] = (__bf16)__expf(x[3]);
        v[4] = (__bf16)__expf(y[0]); v[5] = (__bf16)__expf(y[1]);
        v[6] = (__bf16)__expf(y[2]); v[7] = (__bf16)__expf(y[3]);
      } else {
#pragma unroll
        for (int j = 0; j < 8; ++j)
          v[j] = (__bf16)__expf(trans[(size_t)(32 * kk + 8 * g + j) * N_TAG + row]);
      }
      A[mt][kk] = v;
    }
  }

  // ---- u0 init (all 16 cols identical; col c padded stride) ----
  for (int idx = tid; idx < 16 * N_TAG; idx += 128) {
    int c = idx >> 7, row = idx & 127;
    float v;
    if (dir == 0) {
      v = (row == START_TAG) ? 1.0f : 0.0f;
    } else {
      v = __expf(trans[STOP_TAG * N_TAG + row] +
                 fbase[(size_t)(T_LEN - 1) * N_TAG + row]);
    }
    u_lds[0][c * PADC + row] = (__bf16)v;
  }

  // ---- feat ring: 1 f32/lane (rows [64h,64h+64)); slot s <-> t==s mod 4 ----
  float Lr[4];
#pragma unroll
  for (int s = 0; s < 4; ++s)
    Lr[s] = fbase[(size_t)(T0 + TS * s) * N_TAG + 64 * h + lane];
  Lr[0] = __expf(Lr[0]);
  float logZ = 0.0f;
  const f32x4 FZ = {0.f, 0.f, 0.f, 0.f};
  __syncthreads();

  // EF[mt][r] = ef[64h+16mt+4g+r] <- bpermute lane (16mt+4g+r) of exp'd ring.
#define ITER(S, SX, KP4, DOREN)                                               \
  {                                                                           \
    const int PAR_ = (S) & 1;                                                 \
    const __bf16* ub_ = u_lds[PAR_] + n * PADC;                               \
    bf16x8 b0_ = *(const bf16x8*)(ub_ + 8 * g);                               \
    bf16x8 b1_ = *(const bf16x8*)(ub_ + 32 + 8 * g);                          \
    bf16x8 b2_ = *(const bf16x8*)(ub_ + 64 + 8 * g);                          \
    bf16x8 b3_ = *(const bf16x8*)(ub_ + 96 + 8 * g);                          \
    f32x4 EF_[4];                                                             \
    _Pragma("unroll") for (int mt_ = 0; mt_ < 4; ++mt_) {                     \
      _Pragma("unroll") for (int r_ = 0; r_ < 4; ++r_)                        \
          EF_[mt_][r_] = __int_as_float(__builtin_amdgcn_ds_bpermute(         \
              64 * mt_ + 16 * g + 4 * r_, __float_as_int(Lr[S])));            \
    }                                                                         \
    f32x4 acc_[4];                                                            \
    _Pragma("unroll") for (int mt_ = 0; mt_ < 4; ++mt_)                       \
        acc_[mt_] = __builtin_amdgcn_mfma_f32_16x16x32_bf16(A[mt_][0], b0_,   \
                                                            FZ, 0, 0, 0);     \
    _Pragma("unroll") for (int mt_ = 0; mt_ < 4; ++mt_)                       \
        acc_[mt_] = __builtin_amdgcn_mfma_f32_16x16x32_bf16(A[mt_][1], b1_,   \
                                                            acc_[mt_], 0, 0, 0);\
    _Pragma("unroll") for (int mt_ = 0; mt_ < 4; ++mt_)                       \
        acc_[mt_] = __builtin_amdgcn_mfma_f32_16x16x32_bf16(A[mt_][2], b2_,   \
                                                            acc_[mt_], 0, 0, 0);\
    _Pragma("unroll") for (int mt_ = 0; mt_ < 4; ++mt_)                       \
        acc_[mt_] = __builtin_amdgcn_mfma_f32_16x16x32_bf16(A[mt_][3], b3_,   \
                                                            acc_[mt_], 0, 0, 0);\
    _Pragma("unroll") for (int mt_ = 0; mt_ < 4; ++mt_) {                     \
      acc_[mt_][0] *= EF_[mt_][0]; acc_[mt_][1] *= EF_[mt_][1];               \
      acc_[mt_][2] *= EF_[mt_][2]; acc_[mt_][3] *= EF_[mt_][3];               \
    }                                                                         \
    if (DOREN) {                                                              \
      float mx_ = acc_[0][0];                                                 \
      _Pragma("unroll") for (int mt_ = 0; mt_ < 4; ++mt_)                     \
          mx_ = fmaxf(mx_, fmaxf(fmaxf(acc_[mt_][0], acc_[mt_][1]),           \
                                 fmaxf(acc_[mt_][2], acc_[mt_][3])));         \
      mx_ = fmaxf(mx_, __shfl_xor(mx_, 16));                                  \
      mx_ = fmaxf(mx_, __shfl_xor(mx_, 32));                                  \
      if (g == 0) MX[h][n] = mx_;                                             \
      BAR();                                                                  \
      float c_ = fmaxf(MX[0][n], MX[1][n]);                                   \
      int eb_ = __float_as_int(c_) & 0x7f800000;                              \
      float inv_ = __int_as_float(0x7f000000 - eb_);                          \
      logZ += (float)((eb_ >> 23) - 127) * 0.69314718056f;                    \
      _Pragma("unroll") for (int mt_ = 0; mt_ < 4; ++mt_) {                   \
        acc_[mt_][0] *= inv_; acc_[mt_][1] *= inv_;                           \
        acc_[mt_][2] *= inv_; acc_[mt_][3] *= inv_;                           \
      }                                                                       \
    }                                                                         \
    __bf16* ud_ = u_lds[PAR_ ^ 1] + n * PADC + 64 * h + 4 * g;                \
    _Pragma("unroll") for (int mt_ = 0; mt_ < 4; ++mt_) {                     \
      union { __bf16 hx[4]; uint2 u2; } pk_;                                  \
      pk_.hx[0] = (__bf16)acc_[mt_][0]; pk_.hx[1] = (__bf16)acc_[mt_][1];     \
      pk_.hx[2] = (__bf16)acc_[mt_][2]; pk_.hx[3] = (__bf16)acc_[mt_][3];     \
      *(uint2*)(ud_ + 16 * mt_) = pk_.u2;                                     \
    }                                                                         \
    Lr[SX] = __expf(Lr[SX]);                                                  \
    Lr[S] = fbase[(size_t)(T0 + TS * (KP4)) * N_TAG + 64 * h + lane];         \
    BAR();                                                                    \
  }

  // ---- 255 full steps + tail = 256 MFMA steps ----
  for (int kb = 0; kb < 63; ++kb) {
    const int k0 = 4 * kb;
    ITER(0, 1, k0 + 4, false);
    ITER(1, 2, k0 + 5, false);
    ITER(2, 3, k0 + 6, false);
    ITER(3, 0, k0 + 7, true);
  }
  ITER(0, 1, 256, false);
  ITER(1, 2, 257, false);
  ITER(2, 3, 258, false);

  // ---- tail (step 255, buffer parity 1): fwd applies ef; bwd raw ----
  float* SC = ws + 2 * 512 * N_TAG;
  {
    const __bf16* ub = u_lds[1] + n * PADC;
    bf16x8 b0 = *(const bf16x8*)(ub + 8 * g);
    bf16x8 b1 = *(const bf16x8*)(ub + 32 + 8 * g);
    bf16x8 b2 = *(const bf16x8*)(ub + 64 + 8 * g);
    bf16x8 b3 = *(const bf16x8*)(ub + 96 + 8 * g);
    f32x4 acc[4];
#pragma unroll
    for (int mt = 0; mt < 4; ++mt)
      acc[mt] = __builtin_amdgcn_mfma_f32_16x16x32_bf16(A[mt][0], b0, FZ, 0, 0, 0);
#pragma unroll
    for (int mt = 0; mt < 4; ++mt)
      acc[mt] = __builtin_amdgcn_mfma_f32_16x16x32_bf16(A[mt][1], b1, acc[mt], 0, 0, 0);
#pragma unroll
    for (int mt = 0; mt < 4; ++mt)
      acc[mt] = __builtin_amdgcn_mfma_f32_16x16x32_bf16(A[mt][2], b2, acc[mt], 0, 0, 0);
#pragma unroll
    for (int mt = 0; mt < 4; ++mt)
      acc[mt] = __builtin_amdgcn_mfma_f32_16x16x32_bf16(A[mt][3], b3, acc[mt], 0, 0, 0);
    if (dir == 0) {
#pragma unroll
      for (int mt = 0; mt < 4; ++mt) {
#pragma unroll
        for (int r = 0; r < 4; ++r)
          acc[mt][r] *= __int_as_float(__builtin_amdgcn_ds_bpermute(
              64 * mt + 16 * g + 4 * r, __float_as_int(Lr[3])));
      }
    }
    // final renorm (cross-wave) so the combine dot can't overflow
    float mx = acc[0][0];
#pragma unroll
    for (int mt = 0; mt < 4; ++mt)
      mx = fmaxf(mx, fmaxf(fmaxf(acc[mt][0], acc[mt][1]),
                           fmaxf(acc[mt][2], acc[mt][3])));
    mx = fmaxf(mx, __shfl_xor(mx, 16));
    mx = fmaxf(mx, __shfl_xor(mx, 32));
    if (g == 0) MX[h][n] = mx;
    BAR();
    float c = fmaxf(MX[0][n], MX[1][n]);
    int eb = __float_as_int(c) & 0x7f800000;
    float inv = __int_as_float(0x7f000000 - eb);
    logZ += (float)((eb >> 23) - 127) * 0.69314718056f;

    // publish final vector (col 0) to ws
    if (n == 0) {
      float* dst = ws + (size_t)(dir ? 512 * N_TAG : 0) + (size_t)b * N_TAG;
#pragma unroll
      for (int mt = 0; mt < 4; ++mt) {
#pragma unroll
        for (int r = 0; r < 4; ++r)
          dst[64 * h + 16 * mt + 4 * g + r] = acc[mt][r] * inv;
      }
    }
    if (tid == 0) SC[dir * 512 + b] = logZ;
  }

  // ---- gold partial: this block covers t in [dir*256, dir*256+256) ----
  {
    float gsum = 0.f;
#pragma unroll
    for (int q = 0; q < 2; ++q) {
      const int t = dir * 256 + 128 * q + tid;
      int tag = tg[t];
      int prev = (t == 0) ? START_TAG : tg[t - 1];
      gsum += trans[(size_t)tag * N_TAG + prev] + fbase[(size_t)t * N_TAG + tag];
      if (t == T_LEN - 1) gsum += trans[STOP_TAG * N_TAG + tag];
    }
#pragma unroll
    for (int s = 32; s; s >>= 1) gsum += __shfl_xor(gsum, s);
    if (lane == 0) GLD[h] = gsum;
    __syncthreads();
    if (tid == 0) SC[1024 + dir * 512 + b] = GLD[0] + GLD[1];
  }
#undef ITER
}

// combine: out[b] = log(u.w) + LZf + LZb - GF - GB
__global__ __launch_bounds__(64)
void crf_combine_kernel(const float* __restrict__ ws, float* __restrict__ out) {
  const int b = blockIdx.x;
  const int l = threadIdx.x;
  const float* uf = ws + (size_t)b * N_TAG;
  const float* wb = ws + (size_t)512 * N_TAG + (size_t)b * N_TAG;
  float sd = uf[l] * wb[l] + uf[l + 64] * wb[l + 64];
#pragma unroll
  for (int s = 32; s; s >>= 1) sd += __shfl_xor(sd, s);
  if (l == 0) {
    const float* SC = ws + 2 * 512 * N_TAG;
    out[b] = __logf(sd) + SC[b] + SC[512 + b] - SC[1024 + b] - SC[1536 + b];
  }
}

extern "C" void kernel_launch(void* const* d_in, const int* in_sizes, int n_in,
                              void* d_out, int out_size, void* d_ws, size_t ws_size,
                              hipStream_t stream) {
  const float* feats = (const float*)d_in[0];
  const float* trans = (const float*)d_in[1];
  const int* tags = (const int*)d_in[2];
  float* out = (float*)d_out;
  float* ws = (float*)d_ws;
  int B = in_sizes[0] / (T_LEN * N_TAG);  // 512
  crf_dp_kernel<<<B * 2, 128, 0, stream>>>(feats, trans, tags, ws);
  crf_combine_kernel<<<B, 64, 0, stream>>>(ws, out);
}